// Round 9
// baseline (162.513 us; speedup 1.0000x reference)
//
#include <hip/hip_runtime.h>
#include <hip/hip_bf16.h>
#include <hip/hip_fp16.h>

// N3 aggregation: C=64, E=32, H=W=128, K=7, PS=7 (PR=3), WS=13 (WR=6), O=169
#define HW 16384

using u16 = unsigned short;
using u32 = unsigned int;
typedef __attribute__((ext_vector_type(2))) float f32x2;

__device__ __forceinline__ u16 f2h(float f) {
    __half h = __float2half(f);
    return __builtin_bit_cast(u16, h);
}
// acc += a.x*b.x + a.y*b.y  (f16 pairs, f32 accumulate)
__device__ __forceinline__ void dot2acc(float& acc, u32 a, u32 b) {
    asm("v_dot2_f32_f16 %0, %1, %2, %0" : "+v"(acc) : "v"(a), "v"(b));
}
#define SELLO 0x05040100u
#define SELHI 0x07060302u

// ---------------------------------------------------------------------------
// K0: transposes + per-pixel norms. grid 64 x 256. one thread per pixel.
// ---------------------------------------------------------------------------
__global__ __launch_bounds__(256) void k_prep(
        const float* __restrict__ x, const float* __restrict__ xe,
        const float* __restrict__ ye,
        u16* __restrict__ xh, float* __restrict__ xeT,
        float* __restrict__ yeT, float* __restrict__ nx, float* __restrict__ ny) {
    int y = blockIdx.x * 256 + threadIdx.x;

#pragma unroll
    for (int c = 0; c < 64; c++)
        xh[c * HW + y] = f2h(x[c * HW + y]);

    float sx = 0.f, sy = 0.f;
#pragma unroll
    for (int e0 = 0; e0 < 32; e0 += 4) {
        float4 v = make_float4(xe[(e0 + 0) * HW + y], xe[(e0 + 1) * HW + y],
                               xe[(e0 + 2) * HW + y], xe[(e0 + 3) * HW + y]);
        *reinterpret_cast<float4*>(xeT + y * 32 + e0) = v;
        sx += v.x * v.x + v.y * v.y + v.z * v.z + v.w * v.w;
        float4 u = make_float4(ye[(e0 + 0) * HW + y], ye[(e0 + 1) * HW + y],
                               ye[(e0 + 2) * HW + y], ye[(e0 + 3) * HW + y]);
        *reinterpret_cast<float4*>(yeT + y * 32 + e0) = u;
        sy += u.x * u.x + u.y * u.y + u.z * u.z + u.w * u.w;
    }
    nx[y] = sx;
    ny[y] = sy;
}

// ---------------------------------------------------------------------------
// K0b: st[y] = (tinv, tinv*Sy), tinv = exp(-boxsum(lt)/49), Sy = boxsum(ny).
// ---------------------------------------------------------------------------
__global__ __launch_bounds__(256) void k_norms(
        const float* __restrict__ ny, const float* __restrict__ lt,
        float2* __restrict__ st) {
    int y = blockIdx.x * 256 + threadIdx.x;
    int py = y >> 7, px = y & 127;
    float s = 0.f, t = 0.f;
    for (int dy = -3; dy <= 3; dy++)
        for (int dx = -3; dx <= 3; dx++) {
            int yy = py + dy, xx = px + dx;
            if ((unsigned)yy < 128u && (unsigned)xx < 128u) {
                int p = yy * 128 + xx;
                s += ny[p];
                t += lt[p];
            }
        }
    float tinv = __expf(-t * (1.0f / 49.0f));
    st[y] = make_float2(tinv, tinv * s);
}

// ---------------------------------------------------------------------------
// K1 v2: logits[o][y] = -tinv*( Sy(y) + boxsum_z( nx(z+o) - 2*ye(z).xe(z+o) ) ).
// grid (13 di, 64 tiles of 16x16), 1024 threads. (unchanged)
// ---------------------------------------------------------------------------
__global__ __launch_bounds__(1024) void k_logits(
        const float* __restrict__ xeT, const float* __restrict__ yeT,
        const float* __restrict__ nxg, const float2* __restrict__ st,
        float* __restrict__ logits) {
#pragma clang fp contract(fast)
    __shared__ __align__(16) char arena[123904];
    float* s_xe = (float*)arena;              // 748 cells * 32 dw, swizzled
    float* s_nx = (float*)(arena + 95744);    // 748
    float* s_d2 = (float*)(arena + 98736);    // 13 * 484
    float* s_hs = (float*)arena;              // overlay after compute: 13*22*16

    int di = blockIdx.x;
    int tile = blockIdx.y;
    int h0 = (tile >> 3) * 16, w0 = (tile & 7) * 16;
    int gr0 = h0 + di - 9, gc0 = w0 - 9;
    int tid = threadIdx.x;

    for (int idx = tid; idx < 748 * 8; idx += 1024) {
        int cell = idx >> 3, q = idx & 7;
        int r = cell / 34, c = cell - r * 34;
        int gy = gr0 + r, gx = gc0 + c;
        float4 v = make_float4(0.f, 0.f, 0.f, 0.f);
        if ((unsigned)gy < 128u && (unsigned)gx < 128u)
            v = *reinterpret_cast<const float4*>(xeT + (size_t)(gy * 128 + gx) * 32 + q * 4);
        *reinterpret_cast<float4*>(s_xe + cell * 32 + ((q ^ (cell & 7)) << 2)) = v;
    }
    for (int idx = tid; idx < 748; idx += 1024) {
        int r = idx / 34, c = idx - r * 34;
        int gy = gr0 + r, gx = gc0 + c;
        float v = 0.f;
        if ((unsigned)gy < 128u && (unsigned)gx < 128u) v = nxg[gy * 128 + gx];
        s_nx[idx] = v;
    }
    __syncthreads();

    if (tid < 484) {
        int zr = tid / 22, zc = tid - zr * 22;
        int gy = h0 - 3 + zr, gx = w0 - 3 + zc;
        bool zin = ((unsigned)gy < 128u) && ((unsigned)gx < 128u);
        f32x2 yv[16];
#pragma unroll
        for (int j = 0; j < 16; j++) yv[j] = (f32x2){0.f, 0.f};
        if (zin) {
            const float* yp = yeT + (size_t)(gy * 128 + gx) * 32;
#pragma unroll
            for (int j = 0; j < 8; j++) {
                float4 t = *reinterpret_cast<const float4*>(yp + j * 4);
                yv[2 * j] = (f32x2){t.x, t.y};
                yv[2 * j + 1] = (f32x2){t.z, t.w};
            }
        }
        int cell0 = zr * 34 + zc;
#pragma unroll
        for (int dj = 0; dj < 13; dj++) {
            int cell = cell0 + dj;
            const float* bp = s_xe + cell * 32;
            int sw = cell & 7;
            f32x2 a0 = {0.f, 0.f}, a1 = {0.f, 0.f};
#pragma unroll
            for (int q = 0; q < 8; q++) {
                float4 xv = *reinterpret_cast<const float4*>(bp + ((q ^ sw) << 2));
                a0 += ((f32x2){xv.x, xv.y}) * yv[2 * q];
                a1 += ((f32x2){xv.z, xv.w}) * yv[2 * q + 1];
            }
            float cr = a0.x + a0.y + a1.x + a1.y;
            float d2v = fmaf(-2.f, cr, s_nx[cell]);
            s_d2[dj * 484 + tid] = zin ? d2v : 0.f;
        }
    }
    __syncthreads();

    for (int idx = tid; idx < 4576; idx += 1024) {
        int dj = idx / 352, rem = idx - dj * 352;
        int r = rem >> 4, c = rem & 15;
        const float* p = s_d2 + dj * 484 + r * 22 + c;
        float s = p[0] + p[1] + p[2] + p[3] + p[4] + p[5] + p[6];
        s_hs[(dj * 22 + r) * 16 + c] = s;
    }
    __syncthreads();

    for (int idx = tid; idx < 3328; idx += 1024) {
        int dj = idx >> 8, rem = idx & 255;
        int i = rem >> 4, jj = rem & 15;
        const float* p = s_hs + (dj * 22 + i) * 16 + jj;
        float s = p[0] + p[16] + p[32] + p[48] + p[64] + p[80] + p[96];
        int y = (h0 + i) * 128 + (w0 + jj);
        float2 ab = st[y];
        logits[(di * 13 + dj) * HW + y] = -fmaf(ab.x, s, ab.y);
    }
}

// ---------------------------------------------------------------------------
// K2: K=7 rounds of exclusion softmax over O=169. grid 512 x 256. (unchanged)
// ---------------------------------------------------------------------------
__global__ __launch_bounds__(256) void k_softmax(
        const float* __restrict__ logits, u16* __restrict__ Wkt) {
    __shared__ float s_lg[169 * 34];
    int tid = threadIdx.x;
    int y0 = blockIdx.x * 32;
    for (int idx = tid; idx < 169 * 32; idx += 256) {
        int o = idx >> 5, p = idx & 31;
        s_lg[o * 34 + p] = logits[o * HW + y0 + p];
    }
    __syncthreads();
    int pix = tid >> 3, t = tid & 7;
    int y = y0 + pix;
    float l[22];
#pragma unroll
    for (int j = 0; j < 22; j++) {
        int o = t + 8 * j;
        l[j] = (o < 169) ? s_lg[o * 34 + pix] : -3e38f;
    }
    u32 wp0[22], wp1[22], wp2[22], wp3[22];
#pragma unroll
    for (int j = 0; j < 22; j++) { wp0[j] = 0u; wp1[j] = 0u; wp2[j] = 0u; wp3[j] = 0u; }

    float e[22];
#pragma unroll
    for (int k = 0; k < 7; k++) {
        float m = -3e38f;
#pragma unroll
        for (int j = 0; j < 22; j++) m = fmaxf(m, l[j]);
        m = fmaxf(m, __shfl_xor(m, 1));
        m = fmaxf(m, __shfl_xor(m, 2));
        m = fmaxf(m, __shfl_xor(m, 4));
        float s = 0.f;
#pragma unroll
        for (int j = 0; j < 22; j++) { e[j] = __expf(l[j] - m); s += e[j]; }
        s += __shfl_xor(s, 1);
        s += __shfl_xor(s, 2);
        s += __shfl_xor(s, 4);
        float rs = 1.0f / s;
#pragma unroll
        for (int j = 0; j < 22; j++) {
            float w = e[j] * rs;
            u32 h = (u32)f2h(w);
            if (k == 0) wp0[j] |= h;
            else if (k == 1) wp0[j] |= h << 16;
            else if (k == 2) wp1[j] |= h;
            else if (k == 3) wp1[j] |= h << 16;
            else if (k == 4) wp2[j] |= h;
            else if (k == 5) wp2[j] |= h << 16;
            else wp3[j] |= h;
            if (k < 6) l[j] += __logf(fmaxf(1.0f - w, 1e-6f));
        }
    }
#pragma unroll
    for (int j = 0; j < 22; j++) {
        int o = t + 8 * j;
        if (o < 169)
            *reinterpret_cast<uint4*>(Wkt + (o * HW + y) * 8) =
                make_uint4(wp0[j], wp1[j], wp2[j], wp3[j]);
    }
}

// ---------------------------------------------------------------------------
// K2b v2: 7x7 boxsum of Wkt(f16) -> PAIR-PACKED WsP[o2][y][8 u32],
// u32[k] = (f16 w(di,2djp,k) , f16 w(di,2djp+1,k)); slot 7 = 0. (unchanged)
// ---------------------------------------------------------------------------
__global__ __launch_bounds__(256) void k_wsum(
        const u16* __restrict__ Wkt, u32* __restrict__ WsP) {
    __shared__ u16 s_w[38 * 39 * 8];   // [row][col pad39][k8]
    __shared__ u16 s_v[32 * 38 * 8];   // [outrow][col][k8] f16 vertical sums
    int o2 = blockIdx.x;
    int di = o2 / 7, djp = o2 - di * 7;
    int oA = di * 13 + 2 * djp;
    bool hasB = (djp < 6);
    int tile = blockIdx.y;
    int h0 = (tile >> 2) * 32, w0 = (tile & 3) * 32;
    int tid = threadIdx.x;

    auto stage = [&](int o) {
        const u16* src = Wkt + (size_t)o * (HW * 8);
        for (int idx = tid; idx < 38 * 38; idx += 256) {
            int r = idx / 38, c = idx - r * 38;
            int gy = h0 - 3 + r, gx = w0 - 3 + c;
            uint4 v = make_uint4(0u, 0u, 0u, 0u);
            if ((unsigned)gy < 128u && (unsigned)gx < 128u)
                v = *reinterpret_cast<const uint4*>(src + (gy * 128 + gx) * 8);
            *reinterpret_cast<uint4*>(s_w + (r * 39 + c) * 8) = v;
        }
    };
    auto vert = [&]() {
        for (int u = tid; u < 1216; u += 256) {   // 32 out-rows x 38 cols
            int r = u / 38, c = u - r * 38;
            __half2 s0 = __builtin_bit_cast(__half2, 0u);
            __half2 s1 = s0, s2 = s0, s3 = s0;
#pragma unroll
            for (int d = 0; d < 7; d++) {
                uint4 q = *reinterpret_cast<const uint4*>(s_w + ((r + d) * 39 + c) * 8);
                s0 = __hadd2(s0, __builtin_bit_cast(__half2, q.x));
                s1 = __hadd2(s1, __builtin_bit_cast(__half2, q.y));
                s2 = __hadd2(s2, __builtin_bit_cast(__half2, q.z));
                s3 = __hadd2(s3, __builtin_bit_cast(__half2, q.w));
            }
            *reinterpret_cast<uint4*>(s_v + (r * 38 + c) * 8) = make_uint4(
                __builtin_bit_cast(u32, s0), __builtin_bit_cast(u32, s1),
                __builtin_bit_cast(u32, s2), __builtin_bit_cast(u32, s3));
        }
    };
    auto horiz = [&](uint4 (&rr)[4]) {
#pragma unroll
        for (int i = 0; i < 4; i++) {              // 32 rows x 32 out-cols
            int u = tid + i * 256;
            int r = u >> 5, cx = u & 31;
            __half2 s0 = __builtin_bit_cast(__half2, 0u);
            __half2 s1 = s0, s2 = s0, s3 = s0;
#pragma unroll
            for (int d = 0; d < 7; d++) {
                uint4 q = *reinterpret_cast<const uint4*>(s_v + (r * 38 + cx + d) * 8);
                s0 = __hadd2(s0, __builtin_bit_cast(__half2, q.x));
                s1 = __hadd2(s1, __builtin_bit_cast(__half2, q.y));
                s2 = __hadd2(s2, __builtin_bit_cast(__half2, q.z));
                s3 = __hadd2(s3, __builtin_bit_cast(__half2, q.w));
            }
            rr[i] = make_uint4(
                __builtin_bit_cast(u32, s0), __builtin_bit_cast(u32, s1),
                __builtin_bit_cast(u32, s2), __builtin_bit_cast(u32, s3));
        }
    };

    uint4 rA[4], rB[4];
#pragma unroll
    for (int i = 0; i < 4; i++) rB[i] = make_uint4(0u, 0u, 0u, 0u);

    stage(oA);
    __syncthreads();
    vert();
    __syncthreads();
    horiz(rA);
    if (hasB) {
        __syncthreads();           // rA-horiz reads done; safe to overwrite s_w
        stage(oA + 1);
        __syncthreads();
        vert();
        __syncthreads();
        horiz(rB);
    }

#pragma unroll
    for (int i = 0; i < 4; i++) {
        int u = tid + i * 256;
        int r = u >> 5, cx = u & 31;
        int y = (h0 + r) * 128 + (w0 + cx);
        u32* dst = WsP + ((size_t)o2 * HW + y) * 8;
        uint4 lo = make_uint4(
            __builtin_amdgcn_perm(rB[i].x, rA[i].x, SELLO),
            __builtin_amdgcn_perm(rB[i].x, rA[i].x, SELHI),
            __builtin_amdgcn_perm(rB[i].y, rA[i].y, SELLO),
            __builtin_amdgcn_perm(rB[i].y, rA[i].y, SELHI));
        uint4 hi = make_uint4(
            __builtin_amdgcn_perm(rB[i].z, rA[i].z, SELLO),
            __builtin_amdgcn_perm(rB[i].z, rA[i].z, SELHI),
            __builtin_amdgcn_perm(rB[i].w, rA[i].w, SELLO),
            0u);
        *reinterpret_cast<uint4*>(dst) = lo;
        *reinterpret_cast<uint4*>(dst + 4) = hi;
    }
}

// ---------------------------------------------------------------------------
// K3 v8: aggregation. Whole-C blocks (W fetched once) + pair-packed WsP +
// di ping-pong W prefetch + REGISTER-DOUBLE-BUFFERED LDS x reads (hides the
// ~120cy LDS latency that capped v7 at VALUBusy 50%).
// grid 512 tiles (2x16 pix); 512 thr = 32 pix x 16 cc (4ch each).
// s_x [64ch][14r][32c] f16, plane stride 456 u16 (58.4KB -> 2 blocks/CU).
// ---------------------------------------------------------------------------
__global__ __launch_bounds__(512, 2) void k_agg(
        const u16* __restrict__ xh, const u32* __restrict__ WsP,
        float* __restrict__ out) {
    __shared__ u16 s_x[64 * 456];       // [ch][14r][32c], plane pad 456
    int tb = blockIdx.x;                // 64 row-tiles x 8 col-tiles
    int h0 = (tb >> 3) * 2, w0 = (tb & 7) * 16;
    int tid = threadIdx.x;

    // stage: 3584 units = 64ch x 14r x 4 chunks of 8 cols (7 x 512 exact)
#pragma unroll
    for (int i = 0; i < 7; i++) {
        int it = tid + i * 512;
        int ch = it / 56, rem = it - ch * 56;
        int r = rem >> 2, j = rem & 3;
        int gy = h0 - 6 + r, gx0 = w0 - 6 + 8 * j;
        uint4 v = make_uint4(0u, 0u, 0u, 0u);
        if ((unsigned)gy < 128u) {
            const u16* src = xh + (size_t)ch * HW + gy * 128;
            if (gx0 >= 0 && gx0 <= 120) {
                v = *reinterpret_cast<const uint4*>(src + gx0);
            } else {
                auto pk = [&](int gx) -> u32 {
                    u32 lo = ((unsigned)gx < 128u) ? (u32)src[gx] : 0u;
                    u32 hi = ((unsigned)(gx + 1) < 128u) ? (u32)src[gx + 1] : 0u;
                    return lo | (hi << 16);
                };
                v = make_uint4(pk(gx0), pk(gx0 + 2), pk(gx0 + 4), pk(gx0 + 6));
            }
        }
        *reinterpret_cast<uint4*>(s_x + ch * 456 + r * 32 + 8 * j) = v;
    }
    __syncthreads();

    int cc = tid >> 5, pix = tid & 31;      // cc: 16 chunks of 4 ch
    int pr = pix >> 4, pc = pix & 15;       // 2 x 16 pixels
    int y = (h0 + pr) * 128 + (w0 + pc);
    const u32* wsrc = WsP + (size_t)y * 8;
    const u32* s_x32 = reinterpret_cast<const u32*>(s_x);
    u32 sh = (u32)(pc & 1) * 16;
    int base0 = cc * 912 + (pc >> 1);       // dwords; + q*228 + (pr+di)*16

    float acc[7][4];
#pragma unroll
    for (int k = 0; k < 7; k++)
#pragma unroll
        for (int q = 0; q < 4; q++) acc[k][q] = 0.f;

    auto loadW = [&](int di, uint4 (&A)[7], uint4 (&B)[7]) {
        const u32* wdi = wsrc + (size_t)(di * 7) * (HW * 8);
#pragma unroll
        for (int djp = 0; djp < 7; djp++) {
            const u32* wp = wdi + (size_t)djp * (HW * 8);
            A[djp] = *reinterpret_cast<const uint4*>(wp);
            B[djp] = *reinterpret_cast<const uint4*>(wp + 4);
        }
    };
    auto loadX = [&](u32 (&buf)[8], int dwoff) {
        const u32* p = s_x32 + dwoff;
#pragma unroll
        for (int j = 0; j < 8; j++) buf[j] = p[j];
    };
    auto computeQ = [&](const u32 (&f)[8], const uint4 (&A)[7],
                        const uint4 (&B)[7], int q) {
#pragma unroll
        for (int djp = 0; djp < 7; djp++) {
            u32 x2 = __builtin_amdgcn_alignbit(f[djp + 1], f[djp], sh);
            dot2acc(acc[0][q], A[djp].x, x2);
            dot2acc(acc[1][q], A[djp].y, x2);
            dot2acc(acc[2][q], A[djp].z, x2);
            dot2acc(acc[3][q], A[djp].w, x2);
            dot2acc(acc[4][q], B[djp].x, x2);
            dot2acc(acc[5][q], B[djp].y, x2);
            dot2acc(acc[6][q], B[djp].z, x2);
        }
    };
    // register-double-buffered q sweep; leaves xb = next di's plane-0 row
    auto computeDi = [&](int di, int nextdi, const uint4 (&A)[7],
                         const uint4 (&B)[7], u32 (&xb)[8], u32 (&xt)[8]) {
        int ro = base0 + (pr + di) * 16;
        loadX(xt, ro + 228);                          // q=1
        computeQ(xb, A, B, 0);
        loadX(xb, ro + 2 * 228);                      // q=2
        computeQ(xt, A, B, 1);
        loadX(xt, ro + 3 * 228);                      // q=3
        computeQ(xb, A, B, 2);
        loadX(xb, base0 + (pr + nextdi) * 16);        // next di, q=0
        computeQ(xt, A, B, 3);
    };

    uint4 WA[7], WB[7], WC[7], WD[7];
    u32 xb[8], xt[8];
    loadW(0, WA, WB);
    loadX(xb, base0 + pr * 16);
#pragma unroll 1
    for (int di = 0; di < 12; di += 2) {
        loadW(di + 1, WC, WD);     // prefetch next di's W while computing
        computeDi(di, di + 1, WA, WB, xb, xt);
        loadW(di + 2, WA, WB);     // di+2 <= 12 always inside this loop
        computeDi(di + 1, di + 2, WC, WD, xb, xt);
    }
    computeDi(12, 12, WA, WB, xb, xt);

#pragma unroll
    for (int k = 0; k < 7; k++)
#pragma unroll
        for (int q = 0; q < 4; q++)
            out[(k * 64 + cc * 4 + q) * HW + y] = acc[k][q];
}

// ---------------------------------------------------------------------------
extern "C" void kernel_launch(void* const* d_in, const int* in_sizes, int n_in,
                              void* d_out, int out_size, void* d_ws, size_t ws_size,
                              hipStream_t stream) {
    (void)in_sizes; (void)n_in; (void)out_size; (void)ws_size;
    const float* x  = (const float*)d_in[0];
    const float* xe = (const float*)d_in[1];
    const float* ye = (const float*)d_in[2];
    const float* lt = (const float*)d_in[3];
    float* out = (float*)d_out;
    char* ws = (char*)d_ws;

    // layout (98.3 MB total):
    u16*   xh     = (u16*)(ws + 0);            //  2,097,152 B (f16 [64][128][128])
    float* xeT    = (float*)(ws + 2097152u);   //  2,097,152
    float* yeT    = (float*)(ws + 4194304u);   //  2,097,152
    u16*   Wkt    = (u16*)(ws + 6291456u);     // 44,302,336 -> 50,593,792
    float* logits = (float*)(ws + 50593792u);  // 11,075,584 (dead after k_softmax)
    u32*   WsP    = (u32*)(ws + 50593792u);    // 47,710,208 -> 98,304,000 (overlays logits)
    // nx/ny/st overlay Wkt head: written by k_prep/k_norms, last read by
    // k_logits; Wkt is written later by k_softmax.
    float*  nx = (float*)(ws + 6291456u);             // 65,536
    float*  ny = (float*)(ws + 6291456u + 65536u);    // 65,536
    float2* st = (float2*)(ws + 6291456u + 131072u);  // 131,072

    k_prep<<<64, 256, 0, stream>>>(x, xe, ye, xh, xeT, yeT, nx, ny);
    k_norms<<<64, 256, 0, stream>>>(ny, lt, st);
    k_logits<<<dim3(13, 64), 1024, 0, stream>>>(xeT, yeT, nx, st, logits);
    k_softmax<<<512, 256, 0, stream>>>(logits, Wkt);
    k_wsum<<<dim3(91, 16), 256, 0, stream>>>(Wkt, WsP);
    k_agg<<<512, 512, 0, stream>>>(xh, WsP, out);
}